// Round 16
// baseline (263.325 us; speedup 1.0000x reference)
//
#include <hip/hip_runtime.h>

typedef __bf16 bf16_8 __attribute__((ext_vector_type(8)));
typedef float f32x4 __attribute__((ext_vector_type(4)));

#define MFMA16(a, b, c) __builtin_amdgcn_mfma_f32_16x16x32_bf16(a, b, c, 0, 0, 0)

// Problem constants: B=4 V=16 L=1024 C=256 CA=256; BV = B*V = 64.
// MFMA 16x16x32 bf16 fragment layouts (learn_hip m89-verified):
//   A: lane holds row (l&15), k = (l>>4)*8 + j   (8 contiguous bf16 -> 16B load)
//   B: lane holds col (l&15), k = (l>>4)*8 + j
//   C/D: lane holds col (l&15), rows (l>>4)*4 + r (r=0..3)
//
// Global layouts produced by prep/proj (co-designed with consumers):
//   Q  : [bv][1024][256] bf16, plain row-major
//   K  : [bv][1024][256] bf16, XOR-swizzled within rows: elem(r,c) at r*256 + (c ^ ((r&7)*8))
//   Vf : V^T in FRAGMENT-GRANULE order (R16): per 64-k tile kt, granule
//        g = (k2*16 + n)*64 + lane (16B) holds V[k = k2*32 + (lane>>4)*8 .. +7]
//        [ca = n*16 + (lane&15)] -> attn PV B-frag = contiguous 1KB wave load from
//        global (L1-hot, 32KB tile shared by 8 waves). V never goes through LDS.
//   Wf : Q/K/V weights in fragment order per v (R12, proj B-frags = 1KB wave loads)
//   FcF: fc weights, fragment order (R10, -85us on attn)
// Staging via global_load_lds is LINEAR (wave-uniform dest, m104); swizzles live in
// the pre-permuted global source + matching LDS-read XOR (both-sides involution).
//
// Session conclusions (R4-R15, all measured):
//   - Real levers: fragment-order operands (R10: -85us, R12: -75us), counted-vmcnt
//     dbuf pipelines (R9/R12), operand residency (weights/X in regs/LDS).
//   - Dead ends: dispatch remaps beyond XCD-chunking, setprio, barrier pokes,
//     smaller tiles, 32-rows/wave sharing (allocator caps at 128 VGPR + spills).
//   - R16: V -> fragment-order global reads (m169 precedent: dropping V-staging
//     when cache-resident was +26%); K-only staging; LDS 80KB -> 2 blocks/CU.

__device__ __forceinline__ void load_lds16(const char* g, char* l) {
  __builtin_amdgcn_global_load_lds(
      (const __attribute__((address_space(1))) unsigned int*)g,
      (__attribute__((address_space(3))) unsigned int*)l, 16, 0, 0);
}

// ---------------- prep: weights -> Wf fragment order; fc -> FcF; X -> bf16 ----------------
__global__ __launch_bounds__(256) void prep_kernel(
    const float* __restrict__ Qw, const float* __restrict__ Kw,
    const float* __restrict__ Vw, const float* __restrict__ fcw,
    const float* __restrict__ X,
    __bf16* __restrict__ Wfq, __bf16* __restrict__ Wfk,
    __bf16* __restrict__ Wfv, __bf16* __restrict__ fcb,
    __bf16* __restrict__ Xb)
{
  const int bid = blockIdx.x, t = threadIdx.x;
  if (bid < 192) {
    __shared__ __bf16 lds[64][264];  // 64 c-rows x 256 ca, pad 8
    const int m = bid >> 2, cblk = bid & 3;
    const int wsel = m >> 4, v = m & 15;
    const float* src = (wsel == 0 ? Qw : wsel == 1 ? Kw : Vw) + (size_t)v * 65536;
    __bf16* dst = (wsel == 0 ? Wfq : wsel == 1 ? Wfk : Wfv) + (size_t)v * 65536;
    const int c0 = cblk * 64;
    const int cl = t >> 2, seg = t & 3;
#pragma unroll
    for (int i = 0; i < 16; ++i) {
      float4 f = *(const float4*)(src + (size_t)(c0 + cl) * 256 + seg * 64 + i * 4);
      lds[cl][seg * 64 + i * 4 + 0] = (__bf16)f.x;
      lds[cl][seg * 64 + i * 4 + 1] = (__bf16)f.y;
      lds[cl][seg * 64 + i * 4 + 2] = (__bf16)f.z;
      lds[cl][seg * 64 + i * 4 + 3] = (__bf16)f.w;
    }
    __syncthreads();
    // thread t = ca row; emit fragment-ordered granules
    const int nn = t >> 4, l16 = t & 15;
#pragma unroll
    for (int i = 0; i < 8; ++i) {
      bf16_8 vv;
#pragma unroll
      for (int j = 0; j < 8; ++j) vv[j] = lds[i * 8 + j][t];
      const int c = c0 + i * 8;
      const int ks = c >> 5, lg = (c & 31) >> 3;
      const int g = (ks * 16 + nn) * 64 + lg * 16 + l16;
      *(bf16_8*)(dst + (size_t)g * 8) = vv;
    }
  } else if (bid < 208) {
    // fc_w -> fragment-ordered FcF (8192 granules of 16B = 128KB)
    const int g0 = (bid - 192) * 512 + t * 2;
#pragma unroll
    for (int h = 0; h < 2; ++h) {
      int g = g0 + h;
      int ks = g >> 10, n = (g >> 6) & 15, lane = g & 63;
      const float* src = fcw + (size_t)(n * 16 + (lane & 15)) * 256
                             + ks * 32 + (lane >> 4) * 8;
      float4 f0 = *(const float4*)(src);
      float4 f1 = *(const float4*)(src + 4);
      bf16_8 vv;
      vv[0] = (__bf16)f0.x; vv[1] = (__bf16)f0.y; vv[2] = (__bf16)f0.z; vv[3] = (__bf16)f0.w;
      vv[4] = (__bf16)f1.x; vv[5] = (__bf16)f1.y; vv[6] = (__bf16)f1.z; vv[7] = (__bf16)f1.w;
      *(bf16_8*)(fcb + (size_t)g * 8) = vv;
    }
  } else {
    // X f32 -> bf16: 2048 blocks x 256 threads x 32 elems = 16777216
    const size_t base = (size_t)(bid - 208) * 8192 + t * 32;
#pragma unroll
    for (int h = 0; h < 4; ++h) {
      float4 f0 = *(const float4*)(X + base + h * 8);
      float4 f1 = *(const float4*)(X + base + h * 8 + 4);
      bf16_8 vv;
      vv[0] = (__bf16)f0.x; vv[1] = (__bf16)f0.y; vv[2] = (__bf16)f0.z; vv[3] = (__bf16)f0.w;
      vv[4] = (__bf16)f1.x; vv[5] = (__bf16)f1.y; vv[6] = (__bf16)f1.z; vv[7] = (__bf16)f1.w;
      *(bf16_8*)(Xb + base + h * 8) = vv;
    }
  }
}

// ---------------- proj: weights in REGISTERS; X-tile dbuf via global_load_lds (R12) ----------------
__global__ __launch_bounds__(256, 2) void proj_kernel(
    const __bf16* __restrict__ Xb,
    const __bf16* __restrict__ Wfq, const __bf16* __restrict__ Wfk,
    const __bf16* __restrict__ Wfv,
    const float* __restrict__ Qb, const float* __restrict__ Kb,
    const float* __restrict__ Vb,
    __bf16* __restrict__ Qo, __bf16* __restrict__ Ko, __bf16* __restrict__ VTo,
    int bv0)
{
  extern __shared__ char psmem[];
  char* rpb = psmem + 65536;   // repack: row r, col c (bf16) at r*256 + ((c*2)^((r&7)<<4))

  const int t = threadIdx.x;
  const int w = t >> 6, lane = t & 63;
  const int l16 = lane & 15, lg = lane >> 4;

  // remap: XCD x owns contiguous lids -> 8 consecutive bvs per XCD (weights L2-hot)
  const int nwg = gridDim.x * gridDim.y;           // 12 * nb
  const int hw = blockIdx.x + gridDim.x * blockIdx.y;
  int bvl, r12;
  if (nwg % 96 == 0) {
    const int per = nwg >> 3;
    const int lid = (hw & 7) * per + (hw >> 3);
    bvl = lid / 12; r12 = lid - bvl * 12;
  } else { bvl = blockIdx.y; r12 = blockIdx.x; }
  const int z = r12 >> 2, nh = (r12 >> 1) & 1, rh = r12 & 1;
  const int bvg = bv0 + bvl, v = bvg & 15;

  const __bf16* Wf = (z == 0 ? Wfq : z == 1 ? Wfk : Wfv) + (size_t)v * 65536;
  const float* bias = (z == 0 ? Qb : z == 1 ? Kb : Vb) + nh * 128;

  // B-fragments for this block's 32 columns (wave w: col groups nh*8 + w*2 + n)
  bf16_8 bw0[8], bw1[8];
#pragma unroll
  for (int ks = 0; ks < 8; ++ks) {
    const int nnb = nh * 8 + w * 2;
    bw0[ks] = *(const bf16_8*)(Wf + ((size_t)(ks * 16 + nnb) * 64 + lane) * 8);
    bw1[ks] = *(const bf16_8*)(Wf + ((size_t)(ks * 16 + nnb + 1) * 64 + lane) * 8);
  }

  // X tile staging: LDS linear; source pre-permuted so LDS holds the XOR-swizzled
  // tile (read side applies the same XOR). 2048 granules = 8/thread.
  const char* xb = (const char*)(Xb + ((size_t)(bvg * 1024 + rh * 512)) * 256);
  auto stageX = [&](int it, int pb) {
    const char* src0 = xb + (size_t)it * 32768;
    char* dst0 = psmem + pb * 32768;
#pragma unroll
    for (int i = 0; i < 8; ++i) {
      int p = i * 256 + t, r = p >> 5, c16 = p & 31;
      load_lds16(src0 + r * 512 + ((c16 * 16) ^ ((r & 7) << 4)),
                 dst0 + (i * 256 + w * 64) * 16);
    }
  };

  stageX(0, 0);

  const float bn0 = bias[w * 32 + l16];
  const float bn1 = bias[w * 32 + 16 + l16];
  f32x4 zero = {0.f, 0.f, 0.f, 0.f};
  const int xsw = (l16 & 7) << 4;

  for (int it = 0; it < 8; ++it) {
    const int cur = it & 1;
    // barrier A: all waves done with rpb reads (it-1) and X-buf reads (it-1)
    __builtin_amdgcn_s_barrier();
    if (it < 7) {
      stageX(it + 1, cur ^ 1);
      asm volatile("s_waitcnt vmcnt(8)" ::: "memory");   // tile it ready; stores fly
    } else {
      asm volatile("s_waitcnt vmcnt(0)" ::: "memory");
    }
    __builtin_amdgcn_s_barrier();  // barrier B: every wave's slice of tile it in LDS

    f32x4 acc[4][2];
#pragma unroll
    for (int m = 0; m < 4; ++m) { acc[m][0] = zero; acc[m][1] = zero; }

    const char* xt = psmem + cur * 32768 + l16 * 512;
#pragma unroll
    for (int ks = 0; ks < 8; ++ks) {
      const int co = (ks * 64 + lg * 16) ^ xsw;
      bf16_8 af[4];
#pragma unroll
      for (int m = 0; m < 4; ++m)
        af[m] = *(const bf16_8*)(xt + m * 8192 + co);
#pragma unroll
      for (int m = 0; m < 4; ++m) {
        acc[m][0] = MFMA16(af[m], bw0[ks], acc[m][0]);
        acc[m][1] = MFMA16(af[m], bw1[ks], acc[m][1]);
      }
    }

    // repack D (rows m*16+lg*4+j, local col w*32+n*16+l16) + bias, XOR-swizzled
    const int row0 = rh * 512 + it * 64;
#pragma unroll
    for (int n = 0; n < 2; ++n) {
      float bn = n ? bn1 : bn0;
      int col2 = (w * 32 + n * 16 + l16) * 2;
#pragma unroll
      for (int m = 0; m < 4; ++m)
#pragma unroll
        for (int j = 0; j < 4; ++j) {
          int r = m * 16 + lg * 4 + j;
          *(__bf16*)(rpb + r * 256 + (col2 ^ ((r & 7) << 4))) = (__bf16)(acc[m][n][j] + bn);
        }
    }
    asm volatile("s_waitcnt lgkmcnt(0)" ::: "memory");
    __builtin_amdgcn_s_barrier();  // barrier C: rpb complete

    if (z < 2) {
      __bf16* out = (z == 0 ? Qo : Ko) + (size_t)(bvl * 1024 + row0) * 256;
#pragma unroll
      for (int i = 0; i < 4; ++i) {
        int e = i * 256 + t, rr = e >> 4, cl = (e & 15) * 8;   // local col elems
        bf16_8 d = *(const bf16_8*)(rpb + rr * 256 + ((cl * 2) ^ ((rr & 7) << 4)));
        int gcol = (z == 1) ? (nh * 128 + (cl ^ ((rr & 7) * 8))) : (nh * 128 + cl);
        *(bf16_8*)(out + (size_t)rr * 256 + gcol) = d;
      }
    } else {
      // Vf: fragment-granule order. Tile kt = rh*8+it; this block emits granules
      // with n in [nh*8, nh*8+8). Thread t -> lane6 = t&63, gi = t>>6; 4 granules.
      const int kt = rh * 8 + it;
      const int lane6 = t & 63, gi = t >> 6;
      __bf16* dstb = VTo + (size_t)bvl * 262144 + (size_t)kt * 16384;
#pragma unroll
      for (int i = 0; i < 4; ++i) {
        int idx = gi * 4 + i;          // 0..15: k2 = idx>>3, nloc = idx&7
        int k2 = idx >> 3, nloc = idx & 7;
        bf16_8 vv;
#pragma unroll
        for (int j = 0; j < 8; ++j) {
          int r = k2 * 32 + (lane6 >> 4) * 8 + j;     // local k row
          int cl = nloc * 16 + (lane6 & 15);          // local ca col
          vv[j] = *(const __bf16*)(rpb + r * 256 + ((cl * 2) ^ ((r & 7) << 4)));
        }
        *(bf16_8*)(dstb + ((size_t)(k2 * 16 + nh * 8 + nloc) * 64 + lane6) * 8) = vv;
      }
    }
    // no trailing barrier: next it's barrier A is the release point
  }
}

// ---------------- attn: 128-row q-tile, 8 waves; K-only LDS dbuf; V from global frags ----------------
// Loop: barrier A -> stage K(kt+1) -> vmcnt(4) -> barrier B -> compute. V fragments
// read directly from Vf (1KB wave loads, L1-hot: 32KB tile x 8 waves reuse).
// LDS map (81920 B = 80KB -> 2 blocks/CU): K0@0 K1@32768, Pt@65536 ([128 rows][64 k]
// bf16, 128B row stride, XOR swizzle, wave-private rows).
// Va epilogue [128][256] aliases K0+K1 (64KB exact) after a full __syncthreads.
__global__ __launch_bounds__(512, 2) void attn_kernel(
    const __bf16* __restrict__ Qg, const __bf16* __restrict__ Kg,
    const __bf16* __restrict__ VTg, const __bf16* __restrict__ Fc,
    const float* __restrict__ Xg, const float* __restrict__ fc_b,
    const float* __restrict__ gama, float* __restrict__ Out, int bv0)
{
  extern __shared__ char smem[];
  char* ptb = smem + 65536;   // Pt: row r, byte col c2 at r*128 + (c2 ^ ((r&7)<<4))

  const int t = threadIdx.x;
  const int w = t >> 6, lane = t & 63;
  const int l16 = lane & 15, lg = lane >> 4;

  const int nwg = gridDim.x * gridDim.y;       // nb * 8
  const int hw = blockIdx.x + gridDim.x * blockIdx.y;
  int bvl, qb;
  if (nwg == 512) {
    const int x = hw & 7, j = hw >> 3;         // XCD x, within-XCD rank j (0..63)
    bvl = x * 8 + ((j >> 5) << 2) + (j & 3);   // 4-bv group per 32-block round
    qb  = 7 - ((j >> 2) & 7);                  // heavy-first within each round
  } else { bvl = blockIdx.x; qb = 7 - (int)blockIdx.y; }
  const int bvg = bv0 + bvl;
  const int ktmax = 2 * qb + 1;

  const char* Kb = (const char*)(Kg + (size_t)bvl * 262144);
  const __bf16* Vf = VTg + (size_t)bvl * 262144;

  // Q fragments for this wave's 16 rows (rows qb*128 + w*16 + l16)
  bf16_8 qf[8];
  const __bf16* qp = Qg + ((size_t)(bvl * 1024 + qb * 128 + w * 16 + l16)) * 256 + lg * 8;
#pragma unroll
  for (int ks = 0; ks < 8; ++ks) qf[ks] = *(const bf16_8*)(qp + ks * 32);

  f32x4 zero = {0.f, 0.f, 0.f, 0.f};
  f32x4 oacc[16];
#pragma unroll
  for (int n = 0; n < 16; ++n) oacc[n] = zero;
  float rs[4] = {0.f, 0.f, 0.f, 0.f};

  // swizzle helpers: row within tile is congruent to l16 (mod 8) for all frag reads
  const int swz = (l16 & 7) << 4;              // byte XOR, bits 4-6
  const int p1 = (lg * 16) ^ (swz & 0x30);     // low part (bits 4-5)
  const int o_e = swz & 0x40;                  // k-offset 0  ^ bit6
  const int o_o = 64 ^ (swz & 0x40);           // k-offset 64 ^ bit6

  // stage one 32KB K tile = 4 loads/thread (vmcnt-counted)
  auto stage = [&](int kt, int pb) {
    const char* kg = Kb + (size_t)kt * 32768;
    char* kl = smem + pb * 32768;
#pragma unroll
    for (int i = 0; i < 4; ++i) {
      int go = (i * 512 + t) * 16;        // per-lane global offset
      int lo = (i * 512 + w * 64) * 16;   // wave-uniform LDS base (+lane*16 in HW)
      load_lds16(kg + go, kl + lo);
    }
  };

  // prologue: queue tile 0; it is awaited by the kt=0 iteration's vmcnt
  stage(0, 0);

  for (int kt = 0; kt <= ktmax; ++kt) {
    const int cur = kt & 1;

    // barrier A: all waves done READING K buf[cur^1] -> safe to overwrite
    __builtin_amdgcn_s_barrier();
    if (kt < ktmax) {
      stage(kt + 1, cur ^ 1);                       // 4 new loads -> outstanding <=8
      asm volatile("s_waitcnt vmcnt(4)" ::: "memory");   // tile kt's 4 loads done
    } else {
      asm volatile("s_waitcnt vmcnt(0)" ::: "memory");   // final tile: drain
    }
    // barrier B: every wave's slice of tile kt is in LDS
    __builtin_amdgcn_s_barrier();

    const bool skip = (kt * 64) > (qb * 128 + w * 16 + 15);  // wave fully above diagonal
    if (!skip) {
      // ---- S = Q K^T (16 q-rows x 64 k-cols per wave) ----
      const char* krow = smem + cur * 32768 + l16 * 512 + p1;
      f32x4 sacc[4];
#pragma unroll
      for (int n = 0; n < 4; ++n) sacc[n] = zero;
      __builtin_amdgcn_s_setprio(1);
#pragma unroll
      for (int ks = 0; ks < 8; ++ks) {
        const int cb = (ks >> 1) * 128 + ((ks & 1) ? o_o : o_e);
#pragma unroll
        for (int n = 0; n < 4; ++n) {
          bf16_8 kb = *(const bf16_8*)(krow + n * 8192 + cb);
          sacc[n] = MFMA16(qf[ks], kb, sacc[n]);
        }
      }
      __builtin_amdgcn_s_setprio(0);

      // ---- no-max softmax (logits bounded << 88); causal mask on edge tiles ----
      const bool edge = (kt * 64 + 63) > (qb * 128 + w * 16);
      const int qrow = qb * 128 + w * 16 + lg * 4;
#pragma unroll
      for (int n = 0; n < 4; ++n) {
        int kglob = kt * 64 + n * 16 + l16;
        int c2 = (n * 16 + l16) * 2;
#pragma unroll
        for (int j = 0; j < 4; ++j) {
          float p = __expf(sacc[n][j]);
          if (edge && kglob > qrow + j) p = 0.f;
          rs[j] += p;
          int r = w * 16 + lg * 4 + j;
          *(__bf16*)(ptb + r * 128 + (c2 ^ ((r & 7) << 4))) = (__bf16)p;
        }
      }
      // Pt rows are wave-private: only this wave's LDS ops need draining, no barrier
      asm volatile("s_waitcnt lgkmcnt(0)" ::: "memory");

      // ---- O += P V: V fragments straight from global (1KB wave loads, L1-hot) ----
      const __bf16* vt = Vf + (size_t)kt * 16384;
      const int prow = (w * 16 + l16) * 128;
      __builtin_amdgcn_s_setprio(1);
#pragma unroll
      for (int k2 = 0; k2 < 2; ++k2) {
        bf16_8 pa = *(const bf16_8*)(ptb + prow + ((k2 * 64 + lg * 16) ^ ((l16 & 7) << 4)));
#pragma unroll
        for (int n = 0; n < 16; ++n) {
          bf16_8 vv = *(const bf16_8*)(vt + ((size_t)(k2 * 16 + n) * 64 + lane) * 8);
          oacc[n] = MFMA16(pa, vv, oacc[n]);
        }
      }
      __builtin_amdgcn_s_setprio(0);
    }
    // no trailing barrier: next iteration's barrier A provides the release point
  }

  // full barrier (drains everything) before aliasing K buffers with Va
  __syncthreads();

  // finalize row sums (partials across the 16 l16 lanes of each lg group)
#pragma unroll
  for (int j = 0; j < 4; ++j) {
    float s = rs[j];
    s += __shfl_xor(s, 1); s += __shfl_xor(s, 2);
    s += __shfl_xor(s, 4); s += __shfl_xor(s, 8);
    rs[j] = 1.0f / s;
  }

  // Va -> LDS (aliases K0+K1, 64KB exact), swizzled [128][256]
  __bf16* Va = (__bf16*)smem;
#pragma unroll
  for (int n = 0; n < 16; ++n) {
#pragma unroll
    for (int j = 0; j < 4; ++j) {
      int r = w * 16 + lg * 4 + j;
      int c = n * 16 + l16;
      Va[r * 256 + (c ^ ((r & 7) * 8))] = (__bf16)(oacc[n][j] * rs[j]);
    }
  }
  __syncthreads();

  // fc GEMM: FcF fragment-ordered -> each fb read is a contiguous 1KB wave load
  f32x4 facc[16];
#pragma unroll
  for (int n = 0; n < 16; ++n) facc[n] = zero;
#pragma unroll
  for (int ks = 0; ks < 8; ++ks) {
    int cc = (ks * 32 + lg * 8) ^ ((l16 & 7) * 8);
    bf16_8 pa = *(const bf16_8*)(Va + (w * 16 + l16) * 256 + cc);
    const __bf16* fp = Fc + (size_t)ks * 8192 + lane * 8;
#pragma unroll
    for (int n = 0; n < 16; ++n) {
      bf16_8 fb = *(const bf16_8*)(fp + n * 512);
      facc[n] = MFMA16(pa, fb, facc[n]);
    }
  }

  // out = X + (fc + fc_b) * gama
  const float g = gama[0];
  const size_t base = ((size_t)(bvg * 1024 + qb * 128 + w * 16)) * 256;
#pragma unroll
  for (int n = 0; n < 16; ++n) {
    int col = n * 16 + l16;
    float fbc = fc_b[col];
#pragma unroll
    for (int j = 0; j < 4; ++j) {
      size_t idx = base + (size_t)(lg * 4 + j) * 256 + col;
      Out[idx] = Xg[idx] + (facc[n][j] + fbc) * g;
    }
  }
}

extern "C" void kernel_launch(void* const* d_in, const int* in_sizes, int n_in,
                              void* d_out, int out_size, void* d_ws, size_t ws_size,
                              hipStream_t stream) {
  const float* X    = (const float*)d_in[0];
  const float* Qw   = (const float*)d_in[1];
  const float* Kw   = (const float*)d_in[2];
  const float* Vw   = (const float*)d_in[3];
  const float* Qb   = (const float*)d_in[4];
  const float* Kb   = (const float*)d_in[5];
  const float* Vb   = (const float*)d_in[6];
  const float* gama = (const float*)d_in[7];
  const float* fcw  = (const float*)d_in[8];
  const float* fcb  = (const float*)d_in[9];
  float* out = (float*)d_out;

  char* ws = (char*)d_ws;
  const size_t wbytes = (size_t)(6u << 20) + (128u << 10) + (32u << 20); // Wf + fc + Xbf
  const size_t perbv  = 3ull * 1024 * 256 * 2;             // Q + K + Vf per bv (1.5MB)
  if (ws_size < wbytes + perbv) return;  // workspace too small: fail visibly, no OOB
  int chunk = (int)((ws_size - wbytes) / perbv);
  if (chunk > 64) chunk = 64;
  int nchunks = (64 + chunk - 1) / chunk;
  chunk = (64 + nchunks - 1) / nchunks;

  __bf16* Wfq = (__bf16*)(ws);
  __bf16* Wfk = (__bf16*)(ws + (2u << 20));
  __bf16* Wfv = (__bf16*)(ws + (4u << 20));
  __bf16* Fcb = (__bf16*)(ws + (6u << 20));
  __bf16* Xb  = (__bf16*)(ws + (6u << 20) + (128u << 10));
  __bf16* Qo  = (__bf16*)(ws + wbytes);
  __bf16* Ko  = Qo + (size_t)chunk * 262144;
  __bf16* VTo = Ko + (size_t)chunk * 262144;

  prep_kernel<<<2256, 256, 0, stream>>>(Qw, Kw, Vw, fcw, X, Wfq, Wfk, Wfv, Fcb, Xb);

  const int psmem = 2 * 32768 + 64 * 128 * 2;             // 81920 B -> 2 blocks/CU
  (void)hipFuncSetAttribute(reinterpret_cast<const void*>(proj_kernel),
                            hipFuncAttributeMaxDynamicSharedMemorySize, psmem);
  const int smem = 2 * 32768 + 128 * 128;                 // 81920 B -> 2 blocks/CU
  (void)hipFuncSetAttribute(reinterpret_cast<const void*>(attn_kernel),
                            hipFuncAttributeMaxDynamicSharedMemorySize, smem);

  for (int bv0 = 0; bv0 < 64; bv0 += chunk) {
    int nb = 64 - bv0; if (nb > chunk) nb = chunk;
    proj_kernel<<<dim3(12, nb), 256, psmem, stream>>>(Xb, Wfq, Wfk, Wfv, Qb, Kb, Vb,
                                                      Qo, Ko, VTo, bv0);
    attn_kernel<<<dim3(nb, 8), 512, smem, stream>>>(Qo, Ko, VTo, Fcb, X, fcb, gama,
                                                    out, bv0);
  }
}

// Round 17
// 164.225 us; speedup vs baseline: 1.6034x; 1.6034x over previous
//
#include <hip/hip_runtime.h>

typedef __bf16 bf16_8 __attribute__((ext_vector_type(8)));
typedef float f32x4 __attribute__((ext_vector_type(4)));

#define MFMA16(a, b, c) __builtin_amdgcn_mfma_f32_16x16x32_bf16(a, b, c, 0, 0, 0)

// Problem constants: B=4 V=16 L=1024 C=256 CA=256; BV = B*V = 64.
// MFMA 16x16x32 bf16 fragment layouts (learn_hip m89-verified):
//   A: lane holds row (l&15), k = (l>>4)*8 + j   (8 contiguous bf16 -> 16B load)
//   B: lane holds col (l&15), k = (l>>4)*8 + j
//   C/D: lane holds col (l&15), rows (l>>4)*4 + r (r=0..3)
//
// Global layouts produced by prep/proj (co-designed with consumers):
//   Q  : [bv][1024][256] bf16, plain row-major
//   K  : [bv][1024][256] bf16, XOR-swizzled within rows: elem(r,c) at r*256 + (c ^ ((r&7)*8))
//   V^T: [bv][16 tiles][256 ca][64 k] bf16, tile pos ca*64+q*8+j holds V[k=(q^(ca&7))*8+j][ca]
//   Wf : Q/K/V weights in FRAGMENT ORDER per v (R12, proj B-frags = 1KB wave loads)
//   FcF: fc weights, fragment order (R10, -85us on attn)
// Staging via global_load_lds is LINEAR (wave-uniform dest, m104); swizzles live in
// the pre-permuted global source + matching LDS-read XOR (both-sides involution).
//
// Session conclusions (R4-R16, all measured):
//   - Real levers: fragment-order operands OUTSIDE inner loops (R10: -85us, R12:
//     -75us), counted-vmcnt dbuf pipelines (R9/R12), operand residency.
//   - Dead ends: dispatch remaps beyond XCD-chunking, setprio, barrier pokes,
//     smaller tiles, 32-rows/wave sharing (allocator caps at 128 VGPR + spills,
//     R13/R14), V-from-global inside the PV loop (R16: +140us — VMEM issue/latency
//     >> ds_read even L1-hot; fragment-order global reads only pay off outside
//     latency-critical loops).
//   - This file = R12/R15 configuration, the session-best measurement (168us).

__device__ __forceinline__ void load_lds16(const char* g, char* l) {
  __builtin_amdgcn_global_load_lds(
      (const __attribute__((address_space(1))) unsigned int*)g,
      (__attribute__((address_space(3))) unsigned int*)l, 16, 0, 0);
}

// ---------------- prep: weights -> Wf fragment order; fc -> FcF; X -> bf16 ----------------
__global__ __launch_bounds__(256) void prep_kernel(
    const float* __restrict__ Qw, const float* __restrict__ Kw,
    const float* __restrict__ Vw, const float* __restrict__ fcw,
    const float* __restrict__ X,
    __bf16* __restrict__ Wfq, __bf16* __restrict__ Wfk,
    __bf16* __restrict__ Wfv, __bf16* __restrict__ fcb,
    __bf16* __restrict__ Xb)
{
  const int bid = blockIdx.x, t = threadIdx.x;
  if (bid < 192) {
    __shared__ __bf16 lds[64][264];  // 64 c-rows x 256 ca, pad 8
    const int m = bid >> 2, cblk = bid & 3;
    const int wsel = m >> 4, v = m & 15;
    const float* src = (wsel == 0 ? Qw : wsel == 1 ? Kw : Vw) + (size_t)v * 65536;
    __bf16* dst = (wsel == 0 ? Wfq : wsel == 1 ? Wfk : Wfv) + (size_t)v * 65536;
    const int c0 = cblk * 64;
    const int cl = t >> 2, seg = t & 3;
#pragma unroll
    for (int i = 0; i < 16; ++i) {
      float4 f = *(const float4*)(src + (size_t)(c0 + cl) * 256 + seg * 64 + i * 4);
      lds[cl][seg * 64 + i * 4 + 0] = (__bf16)f.x;
      lds[cl][seg * 64 + i * 4 + 1] = (__bf16)f.y;
      lds[cl][seg * 64 + i * 4 + 2] = (__bf16)f.z;
      lds[cl][seg * 64 + i * 4 + 3] = (__bf16)f.w;
    }
    __syncthreads();
    // thread t = ca row; emit fragment-ordered granules
    const int nn = t >> 4, l16 = t & 15;
#pragma unroll
    for (int i = 0; i < 8; ++i) {
      bf16_8 vv;
#pragma unroll
      for (int j = 0; j < 8; ++j) vv[j] = lds[i * 8 + j][t];
      const int c = c0 + i * 8;
      const int ks = c >> 5, lg = (c & 31) >> 3;
      const int g = (ks * 16 + nn) * 64 + lg * 16 + l16;
      *(bf16_8*)(dst + (size_t)g * 8) = vv;
    }
  } else if (bid < 208) {
    // fc_w -> fragment-ordered FcF (8192 granules of 16B = 128KB)
    const int g0 = (bid - 192) * 512 + t * 2;
#pragma unroll
    for (int h = 0; h < 2; ++h) {
      int g = g0 + h;
      int ks = g >> 10, n = (g >> 6) & 15, lane = g & 63;
      const float* src = fcw + (size_t)(n * 16 + (lane & 15)) * 256
                             + ks * 32 + (lane >> 4) * 8;
      float4 f0 = *(const float4*)(src);
      float4 f1 = *(const float4*)(src + 4);
      bf16_8 vv;
      vv[0] = (__bf16)f0.x; vv[1] = (__bf16)f0.y; vv[2] = (__bf16)f0.z; vv[3] = (__bf16)f0.w;
      vv[4] = (__bf16)f1.x; vv[5] = (__bf16)f1.y; vv[6] = (__bf16)f1.z; vv[7] = (__bf16)f1.w;
      *(bf16_8*)(fcb + (size_t)g * 8) = vv;
    }
  } else {
    // X f32 -> bf16: 2048 blocks x 256 threads x 32 elems = 16777216
    const size_t base = (size_t)(bid - 208) * 8192 + t * 32;
#pragma unroll
    for (int h = 0; h < 4; ++h) {
      float4 f0 = *(const float4*)(X + base + h * 8);
      float4 f1 = *(const float4*)(X + base + h * 8 + 4);
      bf16_8 vv;
      vv[0] = (__bf16)f0.x; vv[1] = (__bf16)f0.y; vv[2] = (__bf16)f0.z; vv[3] = (__bf16)f0.w;
      vv[4] = (__bf16)f1.x; vv[5] = (__bf16)f1.y; vv[6] = (__bf16)f1.z; vv[7] = (__bf16)f1.w;
      *(bf16_8*)(Xb + base + h * 8) = vv;
    }
  }
}

// ---------------- proj: weights in REGISTERS; X-tile dbuf via global_load_lds (R12) ----------------
__global__ __launch_bounds__(256, 2) void proj_kernel(
    const __bf16* __restrict__ Xb,
    const __bf16* __restrict__ Wfq, const __bf16* __restrict__ Wfk,
    const __bf16* __restrict__ Wfv,
    const float* __restrict__ Qb, const float* __restrict__ Kb,
    const float* __restrict__ Vb,
    __bf16* __restrict__ Qo, __bf16* __restrict__ Ko, __bf16* __restrict__ VTo,
    int bv0)
{
  extern __shared__ char psmem[];
  char* rpb = psmem + 65536;   // repack: row r, col c (bf16) at r*256 + ((c*2)^((r&7)<<4))

  const int t = threadIdx.x;
  const int w = t >> 6, lane = t & 63;
  const int l16 = lane & 15, lg = lane >> 4;

  // remap: XCD x owns contiguous lids -> 8 consecutive bvs per XCD (weights L2-hot)
  const int nwg = gridDim.x * gridDim.y;           // 12 * nb
  const int hw = blockIdx.x + gridDim.x * blockIdx.y;
  int bvl, r12;
  if (nwg % 96 == 0) {
    const int per = nwg >> 3;
    const int lid = (hw & 7) * per + (hw >> 3);
    bvl = lid / 12; r12 = lid - bvl * 12;
  } else { bvl = blockIdx.y; r12 = blockIdx.x; }
  const int z = r12 >> 2, nh = (r12 >> 1) & 1, rh = r12 & 1;
  const int bvg = bv0 + bvl, v = bvg & 15;

  const __bf16* Wf = (z == 0 ? Wfq : z == 1 ? Wfk : Wfv) + (size_t)v * 65536;
  const float* bias = (z == 0 ? Qb : z == 1 ? Kb : Vb) + nh * 128;

  // B-fragments for this block's 32 columns (wave w: col groups nh*8 + w*2 + n)
  bf16_8 bw0[8], bw1[8];
#pragma unroll
  for (int ks = 0; ks < 8; ++ks) {
    const int nnb = nh * 8 + w * 2;
    bw0[ks] = *(const bf16_8*)(Wf + ((size_t)(ks * 16 + nnb) * 64 + lane) * 8);
    bw1[ks] = *(const bf16_8*)(Wf + ((size_t)(ks * 16 + nnb + 1) * 64 + lane) * 8);
  }

  // X tile staging: LDS linear; source pre-permuted so LDS holds the XOR-swizzled
  // tile (read side applies the same XOR). 2048 granules = 8/thread.
  const char* xb = (const char*)(Xb + ((size_t)(bvg * 1024 + rh * 512)) * 256);
  auto stageX = [&](int it, int pb) {
    const char* src0 = xb + (size_t)it * 32768;
    char* dst0 = psmem + pb * 32768;
#pragma unroll
    for (int i = 0; i < 8; ++i) {
      int p = i * 256 + t, r = p >> 5, c16 = p & 31;
      load_lds16(src0 + r * 512 + ((c16 * 16) ^ ((r & 7) << 4)),
                 dst0 + (i * 256 + w * 64) * 16);
    }
  };

  stageX(0, 0);

  const float bn0 = bias[w * 32 + l16];
  const float bn1 = bias[w * 32 + 16 + l16];
  f32x4 zero = {0.f, 0.f, 0.f, 0.f};
  const int xsw = (l16 & 7) << 4;

  for (int it = 0; it < 8; ++it) {
    const int cur = it & 1;
    // barrier A: all waves done with rpb reads (it-1) and X-buf reads (it-1)
    __builtin_amdgcn_s_barrier();
    if (it < 7) {
      stageX(it + 1, cur ^ 1);
      asm volatile("s_waitcnt vmcnt(8)" ::: "memory");   // tile it ready; stores fly
    } else {
      asm volatile("s_waitcnt vmcnt(0)" ::: "memory");
    }
    __builtin_amdgcn_s_barrier();  // barrier B: every wave's slice of tile it in LDS

    f32x4 acc[4][2];
#pragma unroll
    for (int m = 0; m < 4; ++m) { acc[m][0] = zero; acc[m][1] = zero; }

    const char* xt = psmem + cur * 32768 + l16 * 512;
#pragma unroll
    for (int ks = 0; ks < 8; ++ks) {
      const int co = (ks * 64 + lg * 16) ^ xsw;
      bf16_8 af[4];
#pragma unroll
      for (int m = 0; m < 4; ++m)
        af[m] = *(const bf16_8*)(xt + m * 8192 + co);
#pragma unroll
      for (int m = 0; m < 4; ++m) {
        acc[m][0] = MFMA16(af[m], bw0[ks], acc[m][0]);
        acc[m][1] = MFMA16(af[m], bw1[ks], acc[m][1]);
      }
    }

    // repack D (rows m*16+lg*4+j, local col w*32+n*16+l16) + bias, XOR-swizzled
    const int row0 = rh * 512 + it * 64;
#pragma unroll
    for (int n = 0; n < 2; ++n) {
      float bn = n ? bn1 : bn0;
      int col2 = (w * 32 + n * 16 + l16) * 2;
#pragma unroll
      for (int m = 0; m < 4; ++m)
#pragma unroll
        for (int j = 0; j < 4; ++j) {
          int r = m * 16 + lg * 4 + j;
          *(__bf16*)(rpb + r * 256 + (col2 ^ ((r & 7) << 4))) = (__bf16)(acc[m][n][j] + bn);
        }
    }
    asm volatile("s_waitcnt lgkmcnt(0)" ::: "memory");
    __builtin_amdgcn_s_barrier();  // barrier C: rpb complete

    if (z < 2) {
      __bf16* out = (z == 0 ? Qo : Ko) + (size_t)(bvl * 1024 + row0) * 256;
#pragma unroll
      for (int i = 0; i < 4; ++i) {
        int e = i * 256 + t, rr = e >> 4, cl = (e & 15) * 8;   // local col elems
        bf16_8 d = *(const bf16_8*)(rpb + rr * 256 + ((cl * 2) ^ ((rr & 7) << 4)));
        int gcol = (z == 1) ? (nh * 128 + (cl ^ ((rr & 7) * 8))) : (nh * 128 + cl);
        *(bf16_8*)(out + (size_t)rr * 256 + gcol) = d;
      }
    } else {
      // V^T tile kt = row0>>6; this block's ca range [nh*128, nh*128+128)
      const int kt = rh * 8 + it;
      const int cal = t >> 1, half = t & 1;
      __bf16* dst = VTo + (size_t)bvl * 262144 + (size_t)kt * 16384
                    + (size_t)(nh * 128 + cal) * 64;
#pragma unroll
      for (int i = 0; i < 4; ++i) {
        int q = half * 4 + i;
        int k0 = (q ^ (cal & 7)) * 8;
        bf16_8 vv;
#pragma unroll
        for (int j = 0; j < 8; ++j)
          vv[j] = *(const __bf16*)(rpb + (k0 + j) * 256 + ((cal * 2) ^ (j << 4)));
        *(bf16_8*)(dst + q * 8) = vv;
      }
    }
    // no trailing barrier: next it's barrier A is the release point
  }
}

// ---------------- attn: 128-row q-tile, 8 waves, pipelined staging + coalesced fc (R12) ----------------
// Loop (R9): barrier A -> stage(kt+1) -> vmcnt(8) -> barrier B -> compute.
// LDS map (149504 B): K0@0 K1@32768 V0@65536 V1@98304, Pt@131072 (128x72, wave-private),
// Va epilogue aliases K0+K1 (128x256 swizzled) after a full __syncthreads.
__global__ __launch_bounds__(512, 2) void attn_kernel(
    const __bf16* __restrict__ Qg, const __bf16* __restrict__ Kg,
    const __bf16* __restrict__ VTg, const __bf16* __restrict__ Fc,
    const float* __restrict__ Xg, const float* __restrict__ fc_b,
    const float* __restrict__ gama, float* __restrict__ Out, int bv0)
{
  extern __shared__ char smem[];
  __bf16 (*Pt)[72] = (__bf16(*)[72])(smem + 131072);

  const int t = threadIdx.x;
  const int w = t >> 6, lane = t & 63;
  const int l16 = lane & 15, lg = lane >> 4;

  const int nwg = gridDim.x * gridDim.y;       // nb * 8
  const int hw = blockIdx.x + gridDim.x * blockIdx.y;
  int bvl, qb;
  if (nwg == 512) {
    const int x = hw & 7, j = hw >> 3;         // XCD x, within-XCD rank j (0..63)
    bvl = x * 8 + ((j >> 5) << 2) + (j & 3);   // 4-bv group per 32-block round
    qb  = 7 - ((j >> 2) & 7);                  // heavy-first within each round
  } else { bvl = blockIdx.x; qb = 7 - (int)blockIdx.y; }
  const int bvg = bv0 + bvl;
  const int ktmax = 2 * qb + 1;

  const char* Kb = (const char*)(Kg + (size_t)bvl * 262144);
  const char* Vb = (const char*)(VTg + (size_t)bvl * 262144);

  // Q fragments for this wave's 16 rows (rows qb*128 + w*16 + l16)
  bf16_8 qf[8];
  const __bf16* qp = Qg + ((size_t)(bvl * 1024 + qb * 128 + w * 16 + l16)) * 256 + lg * 8;
#pragma unroll
  for (int ks = 0; ks < 8; ++ks) qf[ks] = *(const bf16_8*)(qp + ks * 32);

  f32x4 zero = {0.f, 0.f, 0.f, 0.f};
  f32x4 oacc[16];
#pragma unroll
  for (int n = 0; n < 16; ++n) oacc[n] = zero;
  float rs[4] = {0.f, 0.f, 0.f, 0.f};

  // swizzle helpers: row within tile is congruent to l16 (mod 8) for all frag reads
  const int swz = (l16 & 7) << 4;              // byte XOR, bits 4-6
  const int p1 = (lg * 16) ^ (swz & 0x30);     // low part (bits 4-5)
  const int o_e = swz & 0x40;                  // k-offset 0  ^ bit6
  const int o_o = 64 ^ (swz & 0x40);           // k-offset 64 ^ bit6

  // stage one 32KB K tile + one 32KB V^T tile = 8 loads/thread (vmcnt-counted)
  auto stage = [&](int kt, int pb) {
    const char* kg = Kb + (size_t)kt * 32768;
    const char* vg = Vb + (size_t)kt * 32768;
    char* kl = smem + pb * 32768;
    char* vl = smem + 65536 + pb * 32768;
#pragma unroll
    for (int i = 0; i < 4; ++i) {
      int go = (i * 512 + t) * 16;        // per-lane global offset
      int lo = (i * 512 + w * 64) * 16;   // wave-uniform LDS base (+lane*16 in HW)
      load_lds16(kg + go, kl + lo);
      load_lds16(vg + go, vl + lo);
    }
  };

  // prologue: queue tile 0; it is awaited by the kt=0 iteration's vmcnt
  stage(0, 0);

  for (int kt = 0; kt <= ktmax; ++kt) {
    const int cur = kt & 1;

    // barrier A: all waves done READING buf[cur^1] (tile kt-1) -> safe to overwrite
    __builtin_amdgcn_s_barrier();
    if (kt < ktmax) {
      stage(kt + 1, cur ^ 1);                       // 8 new loads -> outstanding <=16
      asm volatile("s_waitcnt vmcnt(8)" ::: "memory");   // tile kt's 8 loads done
    } else {
      asm volatile("s_waitcnt vmcnt(0)" ::: "memory");   // final tile: drain
    }
    // barrier B: every wave's slice of tile kt is in LDS
    __builtin_amdgcn_s_barrier();

    const bool skip = (kt * 64) > (qb * 128 + w * 16 + 15);  // wave fully above diagonal
    if (!skip) {
      // ---- S = Q K^T (16 q-rows x 64 k-cols per wave) ----
      const char* krow = smem + cur * 32768 + l16 * 512 + p1;
      f32x4 sacc[4];
#pragma unroll
      for (int n = 0; n < 4; ++n) sacc[n] = zero;
      __builtin_amdgcn_s_setprio(1);
#pragma unroll
      for (int ks = 0; ks < 8; ++ks) {
        const int cb = (ks >> 1) * 128 + ((ks & 1) ? o_o : o_e);
#pragma unroll
        for (int n = 0; n < 4; ++n) {
          bf16_8 kb = *(const bf16_8*)(krow + n * 8192 + cb);
          sacc[n] = MFMA16(qf[ks], kb, sacc[n]);
        }
      }
      __builtin_amdgcn_s_setprio(0);

      // ---- no-max softmax (logits bounded << 88); causal mask on edge tiles ----
      const bool edge = (kt * 64 + 63) > (qb * 128 + w * 16);
      const int qrow = qb * 128 + w * 16 + lg * 4;
#pragma unroll
      for (int n = 0; n < 4; ++n) {
        int kglob = kt * 64 + n * 16 + l16;
#pragma unroll
        for (int j = 0; j < 4; ++j) {
          float p = __expf(sacc[n][j]);
          if (edge && kglob > qrow + j) p = 0.f;
          rs[j] += p;
          Pt[w * 16 + lg * 4 + j][n * 16 + l16] = (__bf16)p;
        }
      }
      // Pt rows are wave-private: only this wave's LDS ops need draining, no barrier
      asm volatile("s_waitcnt lgkmcnt(0)" ::: "memory");

      // ---- O += P V ----
      const char* vrow = smem + 65536 + cur * 32768 + l16 * 128 + p1;
      __builtin_amdgcn_s_setprio(1);
#pragma unroll
      for (int k2 = 0; k2 < 2; ++k2) {
        bf16_8 pa = *(const bf16_8*)&Pt[w * 16 + l16][k2 * 32 + lg * 8];
        const int cb = k2 ? o_o : o_e;
#pragma unroll
        for (int n = 0; n < 16; ++n) {
          bf16_8 vv = *(const bf16_8*)(vrow + n * 2048 + cb);
          oacc[n] = MFMA16(pa, vv, oacc[n]);
        }
      }
      __builtin_amdgcn_s_setprio(0);
    }
    // no trailing barrier: next iteration's barrier A provides the release point
  }

  // full barrier (drains everything) before aliasing K buffers with Va
  __syncthreads();

  // finalize row sums (partials across the 16 l16 lanes of each lg group)
#pragma unroll
  for (int j = 0; j < 4; ++j) {
    float s = rs[j];
    s += __shfl_xor(s, 1); s += __shfl_xor(s, 2);
    s += __shfl_xor(s, 4); s += __shfl_xor(s, 8);
    rs[j] = 1.0f / s;
  }

  // Va -> LDS (aliases K buffers), swizzled [128][256]
  __bf16* Va = (__bf16*)smem;
#pragma unroll
  for (int n = 0; n < 16; ++n) {
#pragma unroll
    for (int j = 0; j < 4; ++j) {
      int r = w * 16 + lg * 4 + j;
      int c = n * 16 + l16;
      Va[r * 256 + (c ^ ((r & 7) * 8))] = (__bf16)(oacc[n][j] * rs[j]);
    }
  }
  __syncthreads();

  // fc GEMM: FcF fragment-ordered -> each fb read is a contiguous 1KB wave load
  f32x4 facc[16];
#pragma unroll
  for (int n = 0; n < 16; ++n) facc[n] = zero;
#pragma unroll
  for (int ks = 0; ks < 8; ++ks) {
    int cc = (ks * 32 + lg * 8) ^ ((l16 & 7) * 8);
    bf16_8 pa = *(const bf16_8*)(Va + (w * 16 + l16) * 256 + cc);
    const __bf16* fp = Fc + (size_t)ks * 8192 + lane * 8;
#pragma unroll
    for (int n = 0; n < 16; ++n) {
      bf16_8 fb = *(const bf16_8*)(fp + n * 512);
      facc[n] = MFMA16(pa, fb, facc[n]);
    }
  }

  // out = X + (fc + fc_b) * gama
  const float g = gama[0];
  const size_t base = ((size_t)(bvg * 1024 + qb * 128 + w * 16)) * 256;
#pragma unroll
  for (int n = 0; n < 16; ++n) {
    int col = n * 16 + l16;
    float fbc = fc_b[col];
#pragma unroll
    for (int j = 0; j < 4; ++j) {
      size_t idx = base + (size_t)(lg * 4 + j) * 256 + col;
      Out[idx] = Xg[idx] + (facc[n][j] + fbc) * g;
    }
  }
}

extern "C" void kernel_launch(void* const* d_in, const int* in_sizes, int n_in,
                              void* d_out, int out_size, void* d_ws, size_t ws_size,
                              hipStream_t stream) {
  const float* X    = (const float*)d_in[0];
  const float* Qw   = (const float*)d_in[1];
  const float* Kw   = (const float*)d_in[2];
  const float* Vw   = (const float*)d_in[3];
  const float* Qb   = (const float*)d_in[4];
  const float* Kb   = (const float*)d_in[5];
  const float* Vb   = (const float*)d_in[6];
  const float* gama = (const float*)d_in[7];
  const float* fcw  = (const float*)d_in[8];
  const float* fcb  = (const float*)d_in[9];
  float* out = (float*)d_out;

  char* ws = (char*)d_ws;
  const size_t wbytes = (size_t)(6u << 20) + (128u << 10) + (32u << 20); // Wf + fc + Xbf
  const size_t perbv  = 3ull * 1024 * 256 * 2;             // Q + K + VT per bv (1.5MB)
  if (ws_size < wbytes + perbv) return;  // workspace too small: fail visibly, no OOB
  int chunk = (int)((ws_size - wbytes) / perbv);
  if (chunk > 64) chunk = 64;
  int nchunks = (64 + chunk - 1) / chunk;
  chunk = (64 + nchunks - 1) / nchunks;

  __bf16* Wfq = (__bf16*)(ws);
  __bf16* Wfk = (__bf16*)(ws + (2u << 20));
  __bf16* Wfv = (__bf16*)(ws + (4u << 20));
  __bf16* Fcb = (__bf16*)(ws + (6u << 20));
  __bf16* Xb  = (__bf16*)(ws + (6u << 20) + (128u << 10));
  __bf16* Qo  = (__bf16*)(ws + wbytes);
  __bf16* Ko  = Qo + (size_t)chunk * 262144;
  __bf16* VTo = Ko + (size_t)chunk * 262144;

  prep_kernel<<<2256, 256, 0, stream>>>(Qw, Kw, Vw, fcw, X, Wfq, Wfk, Wfv, Fcb, Xb);

  const int psmem = 2 * 32768 + 64 * 128 * 2;             // 81920 B -> 2 blocks/CU
  (void)hipFuncSetAttribute(reinterpret_cast<const void*>(proj_kernel),
                            hipFuncAttributeMaxDynamicSharedMemorySize, psmem);
  const int smem = 4 * 32768 + 128 * 72 * 2;              // 149504 B
  (void)hipFuncSetAttribute(reinterpret_cast<const void*>(attn_kernel),
                            hipFuncAttributeMaxDynamicSharedMemorySize, smem);

  for (int bv0 = 0; bv0 < 64; bv0 += chunk) {
    int nb = 64 - bv0; if (nb > chunk) nb = chunk;
    proj_kernel<<<dim3(12, nb), 256, psmem, stream>>>(Xb, Wfq, Wfk, Wfv, Qb, Kb, Vb,
                                                      Qo, Ko, VTo, bv0);
    attn_kernel<<<dim3(nb, 8), 512, smem, stream>>>(Qo, Ko, VTo, Fcb, X, fcb, gama,
                                                    out, bv0);
  }
}